// Round 1
// baseline (355.353 us; speedup 1.0000x reference)
//
#include <hip/hip_runtime.h>
#include <math.h>

#define NHID  1024
#define NCLS  224
#define NTPC  225
#define BATCH 2048

#define KSPLIT 8                     // K-chunks of 128 rows
#define KCH    128
#define NTILES (BATCH / 16)          // 128 sample-tiles for the top GEMM
#define NBOT_BLOCKS (NCLS * KSPLIT)      // 1792
#define NTOP_BLOCKS (NTILES * KSPLIT)    // 1024

// ws layout (bytes):
#define CLS_OFF  0
#define POS_OFF  8192
#define LIST_OFF 16384
#define OFFS_OFF 24576
#define YTOP_OFF 32768
#define YTOP_BYTES (BATCH * NCLS * 4)
#define YBOT_OFF (YTOP_OFF + YTOP_BYTES)
#define YBOT_BYTES (BATCH * NTPC * 4)

// ---------------------------------------------------------------------------
// Pass 0: label decode (int32/int64 autodetect), class/pos, group-by-class.
// ---------------------------------------------------------------------------
__global__ __launch_bounds__(256) void group_kernel(const int* __restrict__ labels,
                                                    int* __restrict__ cls,
                                                    int* __restrict__ pos,
                                                    int* __restrict__ list,
                                                    int* __restrict__ offs) {
    __shared__ int cnt[NCLS];
    __shared__ int sc[256];
    __shared__ int bex[NCLS];
    __shared__ int nz;
    const int tid = threadIdx.x;
    if (tid == 0) nz = 0;
    for (int j = tid; j < NCLS; j += 256) cnt[j] = 0;
    __syncthreads();
    int loc = 0;
    for (int k = 0; k < 4; ++k) {
        int i = tid + 256 * k;
        if (labels[2 * i + 1] != 0) loc = 1;
    }
    if (loc) atomicOr(&nz, 1);
    __syncthreads();
    const bool is64 = (nz == 0);
    int myc[8], myr[8];
#pragma unroll
    for (int k = 0; k < 8; ++k) {
        int i = tid + 256 * k;
        int l = is64 ? labels[2 * i] : labels[i];
        int c = l / NTPC;
        cls[i] = c;
        pos[i] = l - c * NTPC;
        myc[k] = c;
        myr[k] = atomicAdd(&cnt[c], 1);
    }
    __syncthreads();
    int v = (tid < NCLS) ? cnt[tid] : 0;
    sc[tid] = v;
    __syncthreads();
    for (int off = 1; off < 256; off <<= 1) {
        int u = (tid >= off) ? sc[tid - off] : 0;
        __syncthreads();
        sc[tid] += u;
        __syncthreads();
    }
    if (tid < NCLS) {
        int ex = sc[tid] - v;
        bex[tid] = ex;
        offs[tid] = ex;
    }
    if (tid == 0) offs[NCLS] = BATCH;
    __syncthreads();
#pragma unroll
    for (int k = 0; k < 8; ++k) {
        int i = tid + 256 * k;
        list[bex[myc[k]] + myr[k]] = i;
    }
}

// ---------------------------------------------------------------------------
// Pass 1 (fused): K-split partial GEMMs, K-chunk = 128 rows, KSPLIT = 8.
// 2816 blocks (vs 1408): 8 blocks/CU resident (LDS 8 KB, VGPR <= 64) to fix
// the 32% occupancy / latency-bound profile.
// Block-index transpose (c = bi % 224, 224 % 8 == 0) puts all K-chunks of a
// target on the SAME XCD -> atomic output lines stay in one L2 (WRITE_SIZE
// was 4x the output size from cross-XCD evictions), and the class's x
// samples get in-XCD L2 reuse.
// Wave w owns cols 64w..64w+63; acc[16] over the 16 tile samples; ONE
// global_load_dword per h-row, 16 FMAs per load, unroll 8 in flight.
// x tile in LDS xs[h][16], XOR-quad swizzle: staging writes 8-way conflict
// (cheap), compute reads are lane-uniform ds_read_b128 broadcasts.
// ---------------------------------------------------------------------------
template<int YC, bool BOT>
__device__ __forceinline__ void run_tiles(const float* __restrict__ x,
                                          const float* __restrict__ W,
                                          float* __restrict__ y,
                                          const int* __restrict__ list,
                                          int o, int n, int hbase,
                                          float* __restrict__ xs) {
    const int tid = threadIdx.x;
    const int w = tid >> 6, l = tid & 63;
    const int col  = 64 * w + l;
    const int colc = min(col, YC - 1);          // clamp for safe loads
    const bool colok = (col < YC);
    const int r  = tid & 127;                   // staging row within chunk
    const int hs = tid >> 7;                    // sample-half (0: i<8, 1: i>=8)
    const int rq = (r >> 1) & 3;                // staging swizzle key

    for (int tile = 0; tile * 16 < n; ++tile) {
        if (tile) __syncthreads();              // xs reuse vs prior compute reads
        // stage: rows r=tid&127, each thread stages 8 samples of its row.
        // For fixed j, a wave's 64 lanes cover 64 consecutive rows -> 256B
        // coalesced loads of x.
        const float* xrow = x + hbase + r;
#pragma unroll
        for (int j = 0; j < 8; ++j) {
            const int i = hs * 8 + j;
            const int idx = tile * 16 + i;
            const int s = BOT ? list[o + min(idx, n - 1)] : (o + idx);
            xs[(r << 4) + ((((i >> 2) ^ rq) << 2) | (i & 3))] = xrow[(size_t)s * NHID];
        }
        __syncthreads();

        float acc[16];
#pragma unroll
        for (int i = 0; i < 16; ++i) acc[i] = 0.f;

        const float* wr = W + (size_t)hbase * YC + colc;
#pragma unroll 8
        for (int h = 0; h < KCH; ++h) {
            float wv = wr[0];
            const float4* xr = (const float4*)&xs[h << 4];
            const int q = (h >> 1) & 3;
            float4 x0 = xr[q];          // sample quad 0 lives at slot 0^q
            float4 x1 = xr[1 ^ q];
            float4 x2 = xr[2 ^ q];
            float4 x3 = xr[3 ^ q];
            acc[0]  = fmaf(x0.x, wv, acc[0]);
            acc[1]  = fmaf(x0.y, wv, acc[1]);
            acc[2]  = fmaf(x0.z, wv, acc[2]);
            acc[3]  = fmaf(x0.w, wv, acc[3]);
            acc[4]  = fmaf(x1.x, wv, acc[4]);
            acc[5]  = fmaf(x1.y, wv, acc[5]);
            acc[6]  = fmaf(x1.z, wv, acc[6]);
            acc[7]  = fmaf(x1.w, wv, acc[7]);
            acc[8]  = fmaf(x2.x, wv, acc[8]);
            acc[9]  = fmaf(x2.y, wv, acc[9]);
            acc[10] = fmaf(x2.z, wv, acc[10]);
            acc[11] = fmaf(x2.w, wv, acc[11]);
            acc[12] = fmaf(x3.x, wv, acc[12]);
            acc[13] = fmaf(x3.y, wv, acc[13]);
            acc[14] = fmaf(x3.z, wv, acc[14]);
            acc[15] = fmaf(x3.w, wv, acc[15]);
            wr += YC;
        }

        const int nt = min(n - tile * 16, 16);
        if (colok) {
            for (int i = 0; i < nt; ++i) {
                const int s = BOT ? list[o + tile * 16 + i] : (o + tile * 16 + i);
                atomicAdd(&y[(size_t)s * YC + col], acc[i]);
            }
        }
    }
}

__global__ __launch_bounds__(256, 8) void partial_kernel(const float* __restrict__ x,
                                                         const float* __restrict__ Wt,
                                                         const float* __restrict__ Wb,
                                                         const int* __restrict__ list,
                                                         const int* __restrict__ offs,
                                                         float* __restrict__ ytop,
                                                         float* __restrict__ ybot) {
    __shared__ __align__(16) float xs[KCH * 16];   // 8 KB
    const int bi = blockIdx.x;
    if (bi < NBOT_BLOCKS) {
        const int c = bi % NCLS;        // 224 % 8 == 0 -> all chunks of class c
        const int k = bi / NCLS;        // land on XCD (c % 8)
        const int o = offs[c];
        const int n = offs[c + 1] - o;
        run_tiles<NTPC, true>(x, Wb + (size_t)c * (NHID * NTPC), ybot, list,
                              o, n, k * KCH, xs);
    } else {
        const int b2 = bi - NBOT_BLOCKS;
        const int st = b2 % NTILES;     // 128 % 8 == 0 -> chunks of tile st
        const int k  = b2 / NTILES;     // land on one XCD
        run_tiles<NCLS, false>(x, Wt, ytop, list, st * 16, 16, k * KCH, xs);
    }
}

// ---------------------------------------------------------------------------
// Pass 2: per-sample dual softmax + product. One wave per sample.
// ---------------------------------------------------------------------------
__global__ __launch_bounds__(256) void finalize_kernel(const float* __restrict__ ytop,
                                                       const float* __restrict__ ybot,
                                                       const float* __restrict__ bt,
                                                       const float* __restrict__ bb,
                                                       const int* __restrict__ cls,
                                                       const int* __restrict__ pos,
                                                       float* __restrict__ out) {
    const int w = threadIdx.x >> 6, l = threadIdx.x & 63;
    const int s = blockIdx.x * 4 + w;
    const int c = cls[s], p = pos[s];

    float v[4];
#pragma unroll
    for (int g = 0; g < 4; ++g) {
        int col = l + 64 * g;
        v[g] = (col < NCLS) ? ytop[(size_t)s * NCLS + col] + bt[col] : -INFINITY;
    }
    float mx = fmaxf(fmaxf(v[0], v[1]), fmaxf(v[2], v[3]));
#pragma unroll
    for (int off = 32; off; off >>= 1) mx = fmaxf(mx, __shfl_xor(mx, off));
    float sum = 0.f, tc = 0.f;
#pragma unroll
    for (int g = 0; g < 4; ++g) {
        int col = l + 64 * g;
        float e = (col < NCLS) ? __expf(v[g] - mx) : 0.f;
        sum += e;
        if (col == c) tc = e;
    }
#pragma unroll
    for (int off = 32; off; off >>= 1) {
        sum += __shfl_xor(sum, off);
        tc  += __shfl_xor(tc, off);
    }
    const float tp = tc / sum;

#pragma unroll
    for (int g = 0; g < 4; ++g) {
        int col = l + 64 * g;
        v[g] = (col < NTPC) ? ybot[(size_t)s * NTPC + col] + bb[c * NTPC + col] : -INFINITY;
    }
    mx = fmaxf(fmaxf(v[0], v[1]), fmaxf(v[2], v[3]));
#pragma unroll
    for (int off = 32; off; off >>= 1) mx = fmaxf(mx, __shfl_xor(mx, off));
    float bsum = 0.f, ep = 0.f;
#pragma unroll
    for (int g = 0; g < 4; ++g) {
        int col = l + 64 * g;
        float e = (col < NTPC) ? __expf(v[g] - mx) : 0.f;
        bsum += e;
        if (col == p) ep = e;
    }
#pragma unroll
    for (int off = 32; off; off >>= 1) bsum += __shfl_xor(bsum, off);
#pragma unroll
    for (int g = 0; g < 4; ++g)
        if (l + 64 * g == p) out[s] = tp * ep / bsum;
}

extern "C" void kernel_launch(void* const* d_in, const int* in_sizes, int n_in,
                              void* d_out, int out_size, void* d_ws, size_t ws_size,
                              hipStream_t stream) {
    const float* inputs = (const float*)d_in[0];
    const int*   labels = (const int*)d_in[1];
    const float* topW   = (const float*)d_in[2];
    const float* topB   = (const float*)d_in[3];
    const float* botW   = (const float*)d_in[4];
    const float* botB   = (const float*)d_in[5];
    float* out = (float*)d_out;

    char* ws   = (char*)d_ws;
    int*   cls = (int*)(ws + CLS_OFF);
    int*   pos = (int*)(ws + POS_OFF);
    int*   lst = (int*)(ws + LIST_OFF);
    int*   off = (int*)(ws + OFFS_OFF);
    float* ytop = (float*)(ws + YTOP_OFF);
    float* ybot = (float*)(ws + YBOT_OFF);

    hipMemsetAsync(ws + YTOP_OFF, 0, YTOP_BYTES + YBOT_BYTES, stream);
    group_kernel<<<1, 256, 0, stream>>>(labels, cls, pos, lst, off);
    partial_kernel<<<NBOT_BLOCKS + NTOP_BLOCKS, 256, 0, stream>>>(
        inputs, topW, botW, lst, off, ytop, ybot);
    finalize_kernel<<<BATCH / 4, 256, 0, stream>>>(ytop, ybot, topB, botB, cls, pos, out);
}

// Round 2
// 338.126 us; speedup vs baseline: 1.0509x; 1.0509x over previous
//
#include <hip/hip_runtime.h>
#include <math.h>

#define NHID  1024
#define NCLS  224
#define NTPC  225
#define BATCH 2048

#define KSPLIT 8                     // K-chunks of 128 rows
#define KCH    128
#define NTILES (BATCH / 16)          // 128 sample-tiles for the top GEMM
#define NBOT_BLOCKS (NCLS * KSPLIT)      // 1792
#define NTOP_BLOCKS (NTILES * KSPLIT)    // 1024

// ws layout (bytes):
#define CLS_OFF  0
#define POS_OFF  8192
#define LIST_OFF 16384
#define OFFS_OFF 24576
#define YTOP_OFF 32768
#define YTOP_BYTES (BATCH * NCLS * 4)
#define YBOT_OFF (YTOP_OFF + YTOP_BYTES)
#define YBOT_BYTES (BATCH * NTPC * 4)

// ---------------------------------------------------------------------------
// Pass 0: label decode (int32/int64 autodetect), class/pos, group-by-class.
// ---------------------------------------------------------------------------
__global__ __launch_bounds__(256) void group_kernel(const int* __restrict__ labels,
                                                    int* __restrict__ cls,
                                                    int* __restrict__ pos,
                                                    int* __restrict__ list,
                                                    int* __restrict__ offs) {
    __shared__ int cnt[NCLS];
    __shared__ int sc[256];
    __shared__ int bex[NCLS];
    __shared__ int nz;
    const int tid = threadIdx.x;
    if (tid == 0) nz = 0;
    for (int j = tid; j < NCLS; j += 256) cnt[j] = 0;
    __syncthreads();
    int loc = 0;
    for (int k = 0; k < 4; ++k) {
        int i = tid + 256 * k;
        if (labels[2 * i + 1] != 0) loc = 1;
    }
    if (loc) atomicOr(&nz, 1);
    __syncthreads();
    const bool is64 = (nz == 0);
    int myc[8], myr[8];
#pragma unroll
    for (int k = 0; k < 8; ++k) {
        int i = tid + 256 * k;
        int l = is64 ? labels[2 * i] : labels[i];
        int c = l / NTPC;
        cls[i] = c;
        pos[i] = l - c * NTPC;
        myc[k] = c;
        myr[k] = atomicAdd(&cnt[c], 1);
    }
    __syncthreads();
    int v = (tid < NCLS) ? cnt[tid] : 0;
    sc[tid] = v;
    __syncthreads();
    for (int off = 1; off < 256; off <<= 1) {
        int u = (tid >= off) ? sc[tid - off] : 0;
        __syncthreads();
        sc[tid] += u;
        __syncthreads();
    }
    if (tid < NCLS) {
        int ex = sc[tid] - v;
        bex[tid] = ex;
        offs[tid] = ex;
    }
    if (tid == 0) offs[NCLS] = BATCH;
    __syncthreads();
#pragma unroll
    for (int k = 0; k < 8; ++k) {
        int i = tid + 256 * k;
        list[bex[myc[k]] + myr[k]] = i;
    }
}

// ---------------------------------------------------------------------------
// Pass 1 (fused): K-split partial GEMMs, K-chunk = 128 rows, KSPLIT = 8.
// 2816 blocks, 8 KB LDS, VGPR <= 64 -> 8 blocks/CU resident.
// Round-1 lesson: launch_bounds(256,8) alone let the compiler squeeze to
// 32 VGPR by SERIALIZING the W loads (1-2 in flight, latency-bound at
// VALUBusy 16%). Fix: explicit ping-pong prefetch arrays wa[8]/wb[8] with
// compile-time indices -- the 8 next-group loads are issued before the
// current group's FMAs, forcing MLP=8 per wave regardless of regalloc.
// Block-index transpose (c = bi % 224, 224 % 8 == 0): all K-chunks of a
// target on the SAME XCD for atomic L2 locality.
// Wave w owns cols 64w..64w+63; acc[16] over the 16 tile samples.
// x tile in LDS xs[h][16], XOR-quad swizzle: compute reads are lane-uniform
// ds_read_b128 broadcasts (conflict-free).
// ---------------------------------------------------------------------------
template<int YC, bool BOT>
__device__ __forceinline__ void run_tiles(const float* __restrict__ x,
                                          const float* __restrict__ W,
                                          float* __restrict__ y,
                                          const int* __restrict__ list,
                                          int o, int n, int hbase,
                                          float* __restrict__ xs) {
    const int tid = threadIdx.x;
    const int w = tid >> 6, l = tid & 63;
    const int col  = 64 * w + l;
    const int colc = min(col, YC - 1);          // clamp for safe loads
    const bool colok = (col < YC);
    const int r  = tid & 127;                   // staging row within chunk
    const int hs = tid >> 7;                    // sample-half (0: i<8, 1: i>=8)
    const int rq = (r >> 1) & 3;                // staging swizzle key

    for (int tile = 0; tile * 16 < n; ++tile) {
        if (tile) __syncthreads();              // xs reuse vs prior compute reads
        // stage: rows r=tid&127, each thread stages 8 samples of its row.
        // For fixed j, a wave's 64 lanes cover 64 consecutive rows -> 256B
        // coalesced loads of x.
        const float* xrow = x + hbase + r;
#pragma unroll
        for (int j = 0; j < 8; ++j) {
            const int i = hs * 8 + j;
            const int idx = tile * 16 + i;
            const int s = BOT ? list[o + min(idx, n - 1)] : (o + idx);
            xs[(r << 4) + ((((i >> 2) ^ rq) << 2) | (i & 3))] = xrow[(size_t)s * NHID];
        }
        __syncthreads();

        float acc[16];
#pragma unroll
        for (int i = 0; i < 16; ++i) acc[i] = 0.f;

        // 16 FMAs per h-row; rows processed in groups of 8 with ping-pong
        // W prefetch (8 global_load_dword in flight at all times).
        auto compute8 = [&](int hb, const float (&wv)[8]) {
#pragma unroll
            for (int j = 0; j < 8; ++j) {
                const float4* xr = (const float4*)&xs[(hb + j) << 4];
                const int q = (j >> 1) & 3;     // == ((hb+j)>>1)&3, hb % 8 == 0
                float4 x0 = xr[q];
                float4 x1 = xr[1 ^ q];
                float4 x2 = xr[2 ^ q];
                float4 x3 = xr[3 ^ q];
                const float wvj = wv[j];
                acc[0]  = fmaf(x0.x, wvj, acc[0]);
                acc[1]  = fmaf(x0.y, wvj, acc[1]);
                acc[2]  = fmaf(x0.z, wvj, acc[2]);
                acc[3]  = fmaf(x0.w, wvj, acc[3]);
                acc[4]  = fmaf(x1.x, wvj, acc[4]);
                acc[5]  = fmaf(x1.y, wvj, acc[5]);
                acc[6]  = fmaf(x1.z, wvj, acc[6]);
                acc[7]  = fmaf(x1.w, wvj, acc[7]);
                acc[8]  = fmaf(x2.x, wvj, acc[8]);
                acc[9]  = fmaf(x2.y, wvj, acc[9]);
                acc[10] = fmaf(x2.z, wvj, acc[10]);
                acc[11] = fmaf(x2.w, wvj, acc[11]);
                acc[12] = fmaf(x3.x, wvj, acc[12]);
                acc[13] = fmaf(x3.y, wvj, acc[13]);
                acc[14] = fmaf(x3.z, wvj, acc[14]);
                acc[15] = fmaf(x3.w, wvj, acc[15]);
            }
        };

        const float* wr = W + (size_t)hbase * YC + colc;
        float wa[8], wb[8];
#pragma unroll
        for (int j = 0; j < 8; ++j) wa[j] = wr[(size_t)j * YC];
#pragma unroll 1
        for (int h0 = 0; h0 < KCH; h0 += 16) {
            const float* wr1 = wr + 8 * YC;
#pragma unroll
            for (int j = 0; j < 8; ++j) wb[j] = wr1[(size_t)j * YC];
            compute8(h0, wa);
            // clamp keeps the (dead) last prefetch in-bounds
            const float* wr2 = wr + ((h0 + 16 < KCH) ? 16 * YC : 0);
#pragma unroll
            for (int j = 0; j < 8; ++j) wa[j] = wr2[(size_t)j * YC];
            compute8(h0 + 8, wb);
            wr += 16 * YC;
        }

        const int nt = min(n - tile * 16, 16);
        if (colok) {
            for (int i = 0; i < nt; ++i) {
                const int s = BOT ? list[o + tile * 16 + i] : (o + tile * 16 + i);
                atomicAdd(&y[(size_t)s * YC + col], acc[i]);
            }
        }
    }
}

__global__ __launch_bounds__(256, 8) void partial_kernel(const float* __restrict__ x,
                                                         const float* __restrict__ Wt,
                                                         const float* __restrict__ Wb,
                                                         const int* __restrict__ list,
                                                         const int* __restrict__ offs,
                                                         float* __restrict__ ytop,
                                                         float* __restrict__ ybot) {
    __shared__ __align__(16) float xs[KCH * 16];   // 8 KB
    const int bi = blockIdx.x;
    if (bi < NBOT_BLOCKS) {
        const int c = bi % NCLS;        // 224 % 8 == 0 -> all chunks of class c
        const int k = bi / NCLS;        // land on XCD (c % 8)
        const int o = offs[c];
        const int n = offs[c + 1] - o;
        run_tiles<NTPC, true>(x, Wb + (size_t)c * (NHID * NTPC), ybot, list,
                              o, n, k * KCH, xs);
    } else {
        const int b2 = bi - NBOT_BLOCKS;
        const int st = b2 % NTILES;     // 128 % 8 == 0 -> chunks of tile st
        const int k  = b2 / NTILES;     // land on one XCD
        run_tiles<NCLS, false>(x, Wt, ytop, list, st * 16, 16, k * KCH, xs);
    }
}

// ---------------------------------------------------------------------------
// Pass 2: per-sample dual softmax + product. One wave per sample.
// ---------------------------------------------------------------------------
__global__ __launch_bounds__(256) void finalize_kernel(const float* __restrict__ ytop,
                                                       const float* __restrict__ ybot,
                                                       const float* __restrict__ bt,
                                                       const float* __restrict__ bb,
                                                       const int* __restrict__ cls,
                                                       const int* __restrict__ pos,
                                                       float* __restrict__ out) {
    const int w = threadIdx.x >> 6, l = threadIdx.x & 63;
    const int s = blockIdx.x * 4 + w;
    const int c = cls[s], p = pos[s];

    float v[4];
#pragma unroll
    for (int g = 0; g < 4; ++g) {
        int col = l + 64 * g;
        v[g] = (col < NCLS) ? ytop[(size_t)s * NCLS + col] + bt[col] : -INFINITY;
    }
    float mx = fmaxf(fmaxf(v[0], v[1]), fmaxf(v[2], v[3]));
#pragma unroll
    for (int off = 32; off; off >>= 1) mx = fmaxf(mx, __shfl_xor(mx, off));
    float sum = 0.f, tc = 0.f;
#pragma unroll
    for (int g = 0; g < 4; ++g) {
        int col = l + 64 * g;
        float e = (col < NCLS) ? __expf(v[g] - mx) : 0.f;
        sum += e;
        if (col == c) tc = e;
    }
#pragma unroll
    for (int off = 32; off; off >>= 1) {
        sum += __shfl_xor(sum, off);
        tc  += __shfl_xor(tc, off);
    }
    const float tp = tc / sum;

#pragma unroll
    for (int g = 0; g < 4; ++g) {
        int col = l + 64 * g;
        v[g] = (col < NTPC) ? ybot[(size_t)s * NTPC + col] + bb[c * NTPC + col] : -INFINITY;
    }
    mx = fmaxf(fmaxf(v[0], v[1]), fmaxf(v[2], v[3]));
#pragma unroll
    for (int off = 32; off; off >>= 1) mx = fmaxf(mx, __shfl_xor(mx, off));
    float bsum = 0.f, ep = 0.f;
#pragma unroll
    for (int g = 0; g < 4; ++g) {
        int col = l + 64 * g;
        float e = (col < NTPC) ? __expf(v[g] - mx) : 0.f;
        bsum += e;
        if (col == p) ep = e;
    }
#pragma unroll
    for (int off = 32; off; off >>= 1) bsum += __shfl_xor(bsum, off);
#pragma unroll
    for (int g = 0; g < 4; ++g)
        if (l + 64 * g == p) out[s] = tp * ep / bsum;
}

extern "C" void kernel_launch(void* const* d_in, const int* in_sizes, int n_in,
                              void* d_out, int out_size, void* d_ws, size_t ws_size,
                              hipStream_t stream) {
    const float* inputs = (const float*)d_in[0];
    const int*   labels = (const int*)d_in[1];
    const float* topW   = (const float*)d_in[2];
    const float* topB   = (const float*)d_in[3];
    const float* botW   = (const float*)d_in[4];
    const float* botB   = (const float*)d_in[5];
    float* out = (float*)d_out;

    char* ws   = (char*)d_ws;
    int*   cls = (int*)(ws + CLS_OFF);
    int*   pos = (int*)(ws + POS_OFF);
    int*   lst = (int*)(ws + LIST_OFF);
    int*   off = (int*)(ws + OFFS_OFF);
    float* ytop = (float*)(ws + YTOP_OFF);
    float* ybot = (float*)(ws + YBOT_OFF);

    hipMemsetAsync(ws + YTOP_OFF, 0, YTOP_BYTES + YBOT_BYTES, stream);
    group_kernel<<<1, 256, 0, stream>>>(labels, cls, pos, lst, off);
    partial_kernel<<<NBOT_BLOCKS + NTOP_BLOCKS, 256, 0, stream>>>(
        inputs, topW, botW, lst, off, ytop, ybot);
    finalize_kernel<<<BATCH / 4, 256, 0, stream>>>(ytop, ybot, topB, botB, cls, pos, out);
}